// Round 7
// baseline (343.265 us; speedup 1.0000x reference)
//
#include <hip/hip_runtime.h>
#include <hip/hip_bf16.h>

#define N_TOT 4096
#define BATCH 2048
#define DIM   256
#define NCLS  100
#define NSLC  4            // csum slices
#define NTILE 32           // 4096 / 128
#define NPAIR 528          // NTILE*(NTILE+1)/2
#define NWORK (NPAIR + NCLS * NSLC)   // 928 blocks

typedef __attribute__((ext_vector_type(8))) short short8;
typedef __attribute__((ext_vector_type(4))) float floatx4;
typedef __attribute__((ext_vector_type(4))) unsigned short ushortx4;

typedef __attribute__((address_space(1))) const unsigned int as1c_uint;
typedef __attribute__((address_space(3))) unsigned int as3_uint;

// async global->LDS, 16B per lane; lds dest is wave-uniform base (+lane*16 by HW)
__device__ __forceinline__ void gload_lds16(const void* g, void* lds_base) {
    __builtin_amdgcn_global_load_lds((as1c_uint*)g, (as3_uint*)lds_base, 16, 0, 0);
}

__device__ __forceinline__ unsigned short f2bf(float x) {
    __hip_bfloat16 h = __float2bfloat16(x);
    return *(unsigned short*)&h;
}

// Grid-wide barrier. Safe because all NWORK blocks are co-resident
// (38.9KB LDS <= 40KB/block and __launch_bounds__(256,4) -> 4 blocks/CU,
// capacity 1024 >= 928). Arrive: agent-scope RMW. Spin: agent-scope atomic
// LOADS (no RMW hammering). threadfence pair = cross-XCD release/acquire.
__device__ __forceinline__ void grid_barrier(int* cnt, int* rel) {
    __syncthreads();
    if (threadIdx.x == 0) {
        __threadfence();   // release this block's prior writes device-wide
        if (__hip_atomic_fetch_add(cnt, 1, __ATOMIC_ACQ_REL,
                                   __HIP_MEMORY_SCOPE_AGENT) == NWORK - 1) {
            __hip_atomic_store(rel, 1, __ATOMIC_RELEASE, __HIP_MEMORY_SCOPE_AGENT);
        } else {
            while (__hip_atomic_load(rel, __ATOMIC_ACQUIRE,
                                     __HIP_MEMORY_SCOPE_AGENT) == 0)
                __builtin_amdgcn_s_sleep(2);
        }
        __threadfence();   // acquire: invalidate stale L1/L2 before reading
    }
    __syncthreads();
}

// ---------------------------------------------------------------------------
// One kernel, three phases separated by grid barriers:
//   A) normalize rows -> zb (bf16) + zf (fp32), labels        [blocks 0..511]
//   B) den MFMA tiles [0..527] / class sums [528..927]
//   C) per-row nom/den + deterministic final reduce           [blocks 0..511]
// ---------------------------------------------------------------------------
__global__ __launch_bounds__(256, 4) void fused_kernel(
        const float* __restrict__ z_i, const float* __restrict__ z_j,
        const float* __restrict__ dist,
        unsigned short* __restrict__ zb, float* __restrict__ zf,
        int* __restrict__ lab,
        float* __restrict__ den_part, float* __restrict__ csum_part,
        float* __restrict__ partial, int* __restrict__ gsync,
        float* __restrict__ out)
{
    __shared__ short tA[2][128 * 32];    // 2 x 8 KB
    __shared__ short tB[2][128 * 32];    // 2 x 8 KB
    __shared__ float red_rs[2][128];
    __shared__ float red_cs[2][128];
    __shared__ float cred[4][DIM];       // csum reduction
    __shared__ float wred[4];
    __shared__ int   amlast;

    const int t = threadIdx.x;
    const int lane = t & 63, wv = t >> 6;
    const int blk = blockIdx.x;

    // ===================== phase A: prep =====================
    if (blk < 512) {
        #pragma unroll
        for (int it = 0; it < 2; ++it) {
            const int n = blk * 8 + it * 4 + wv;
            const float* src = (n < BATCH) ? (z_i + (size_t)n * DIM)
                                           : (z_j + (size_t)(n - BATCH) * DIM);
            const floatx4 v = *(const floatx4*)(src + lane * 4);
            float sq = v[0]*v[0] + v[1]*v[1] + v[2]*v[2] + v[3]*v[3];
            #pragma unroll
            for (int s = 32; s; s >>= 1) sq += __shfl_xor(sq, s);
            const float rn = 1.0f / sqrtf(sq);

            floatx4 zn;
            zn[0] = v[0]*rn; zn[1] = v[1]*rn; zn[2] = v[2]*rn; zn[3] = v[3]*rn;
            *(floatx4*)(zf + (size_t)n * DIM + lane * 4) = zn;
            ushortx4 zp;
            zp[0] = f2bf(zn[0]); zp[1] = f2bf(zn[1]);
            zp[2] = f2bf(zn[2]); zp[3] = f2bf(zn[3]);
            *(ushortx4*)(zb + (size_t)n * DIM + lane * 4) = zp;

            if (n < BATCH) {
                float d0 = 0.f, d1 = 0.f;
                if (lane < 50) {
                    d0 = dist[(size_t)n * NCLS + 2 * lane];
                    d1 = dist[(size_t)n * NCLS + 2 * lane + 1];
                }
                const unsigned long long m0 = __ballot(d0 > 0.5f);
                const unsigned long long m1 = __ballot(d1 > 0.5f);
                if (lane == 0) {
                    const int l = m0 ? 2 * __builtin_ctzll(m0)
                                     : 2 * __builtin_ctzll(m1) + 1;
                    lab[n] = l;
                    lab[n + BATCH] = l;
                }
            }
        }
    }
    grid_barrier(&gsync[0], &gsync[1]);

    // ===================== phase B =====================
    if (blk >= NPAIR) {
        // ---------------- csum path ----------------
        const int b = blk - NPAIR;                 // 0..399
        const int c = b % NCLS;
        const int s = b / NCLS;
        const int m0 = s * 1024 + wv * 256;

        floatx4 acc = {0.f, 0.f, 0.f, 0.f};
        #pragma unroll
        for (int g = 0; g < 4; ++g) {
            const int m = m0 + g * 64 + lane;
            unsigned long long mask = __ballot(lab[m] == c);
            while (mask) {
                const int bit = __builtin_ctzll(mask);
                mask &= mask - 1;
                const int mm = m0 + g * 64 + bit;
                acc += *(const floatx4*)(zf + (size_t)mm * DIM + lane * 4);
            }
        }
        *(floatx4*)&cred[wv][lane * 4] = acc;
        __syncthreads();
        if (t < DIM)
            csum_part[((size_t)s * NCLS + c) * DIM + t] =
                cred[0][t] + cred[1][t] + cred[2][t] + cred[3][t];
    } else {
        // ---------------- den path ----------------
        int p = blk;
        int bi = 0;
        while (p >= NTILE - bi) { p -= NTILE - bi; ++bi; }
        const int bj = bi + p;

        const int wy = wv >> 1, wx = wv & 1;
        const int lr = lane & 15;
        const int lg = lane >> 4;            // 0..3  (16B chunk of the K=32 slab)
        const int sr = lane >> 2;            // 0..15 row-in-q for staging
        const int sslot = lane & 3;          // LDS slot for staging

        const short* z = (const short*)zb;
        const int row0 = bi * 128;
        const int col0 = bj * 128;

        floatx4 acc[4][4] = {};

        auto STAGE = [&](int kt, int buf) {
            #pragma unroll
            for (int qi = 0; qi < 2; ++qi) {
                const int q = wv * 2 + qi;               // 0..7, 1 KB each (16 rows)
                const int r = q * 16 + sr;
                const int g = sslot ^ ((r >> 1) & 3);    // global chunk for this slot
                gload_lds16(z + (size_t)(row0 + r) * DIM + kt * 32 + g * 8,
                            (char*)tA[buf] + q * 1024);
                gload_lds16(z + (size_t)(col0 + r) * DIM + kt * 32 + g * 8,
                            (char*)tB[buf] + q * 1024);
            }
        };
        auto COMPUTE = [&](int buf) {
            short8 a[4], bb[4];
            #pragma unroll
            for (int i = 0; i < 4; ++i) {
                const int row = wy * 64 + i * 16 + lr;
                const int sl  = lg ^ ((row >> 1) & 3);
                a[i] = *(const short8*)((const char*)tA[buf] + row * 64 + sl * 16);
            }
            #pragma unroll
            for (int j = 0; j < 4; ++j) {
                const int col = wx * 64 + j * 16 + lr;
                const int sl  = lg ^ ((col >> 1) & 3);
                bb[j] = *(const short8*)((const char*)tB[buf] + col * 64 + sl * 16);
            }
            #pragma unroll
            for (int i = 0; i < 4; ++i)
                #pragma unroll
                for (int j = 0; j < 4; ++j)
                    acc[i][j] = __builtin_amdgcn_mfma_f32_16x16x32_bf16(a[i], bb[j], acc[i][j], 0, 0, 0);
        };

        STAGE(0, 0);
        __syncthreads();
        int cur = 0;
        #pragma unroll
        for (int kt = 0; kt < 8; ++kt) {
            if (kt < 7) STAGE(kt + 1, cur ^ 1);
            COMPUTE(cur);
            __syncthreads();
            cur ^= 1;
        }

        // epilogue: e = off-diag exp(sim); row sums + col sums
        float rs[4][4] = {};
        float cs[4]    = {};
        #pragma unroll
        for (int i = 0; i < 4; ++i) {
            #pragma unroll
            for (int j = 0; j < 4; ++j) {
                const int gcol = col0 + wx * 64 + j * 16 + lr;
                #pragma unroll
                for (int r = 0; r < 4; ++r) {
                    const int grow = row0 + wy * 64 + i * 16 + lg * 4 + r;
                    const float e = (grow == gcol) ? 0.0f : __expf(acc[i][j][r]);
                    rs[i][r] += e;
                    cs[j]    += e;
                }
            }
        }
        #pragma unroll
        for (int i = 0; i < 4; ++i)
            #pragma unroll
            for (int r = 0; r < 4; ++r) {
                float v = rs[i][r];
                v += __shfl_xor(v, 1); v += __shfl_xor(v, 2);
                v += __shfl_xor(v, 4); v += __shfl_xor(v, 8);
                rs[i][r] = v;
            }
        if (lr == 0)
            #pragma unroll
            for (int i = 0; i < 4; ++i)
                #pragma unroll
                for (int r = 0; r < 4; ++r)
                    red_rs[wx][wy * 64 + i * 16 + lg * 4 + r] = rs[i][r];

        #pragma unroll
        for (int j = 0; j < 4; ++j) {
            float v = cs[j];
            v += __shfl_xor(v, 16); v += __shfl_xor(v, 32);
            cs[j] = v;
        }
        if (lane < 16)
            #pragma unroll
            for (int j = 0; j < 4; ++j)
                red_cs[wy][wx * 64 + j * 16 + lr] = cs[j];

        __syncthreads();
        if (t < 128) {
            den_part[(size_t)bj * N_TOT + row0 + t] = red_rs[0][t] + red_rs[1][t];
            if (bi != bj)
                den_part[(size_t)bi * N_TOT + col0 + t] = red_cs[0][t] + red_cs[1][t];
        }
    }
    grid_barrier(&gsync[32], &gsync[33]);

    // ===================== phase C: finalize =====================
    if (blk < 512) {
        float bsum = 0.0f;
        #pragma unroll
        for (int it = 0; it < 2; ++it) {
            const int n = blk * 8 + it * 4 + wv;
            const int c = lab[n];

            const floatx4 zv = *(const floatx4*)(zf + (size_t)n * DIM + lane * 4);
            floatx4 sv = {0.f, 0.f, 0.f, 0.f};
            #pragma unroll
            for (int s = 0; s < NSLC; ++s)
                sv += *(const floatx4*)(csum_part + ((size_t)s * NCLS + c) * DIM + lane * 4);

            float pd = zv[0]*sv[0] + zv[1]*sv[1] + zv[2]*sv[2] + zv[3]*sv[3];
            float dd = (lane < 32) ? den_part[(size_t)lane * N_TOT + n] : 0.0f;
            #pragma unroll
            for (int sh = 32; sh; sh >>= 1) {
                pd += __shfl_xor(pd, sh);
                dd += __shfl_xor(dd, sh);
            }
            bsum += (pd - 1.0f) / dd;
        }

        if (lane == 0) wred[wv] = bsum;
        __syncthreads();
        if (t == 0) {
            partial[blk] = wred[0] + wred[1] + wred[2] + wred[3];
            __threadfence();
            amlast = (__hip_atomic_fetch_add(&gsync[48], 1, __ATOMIC_ACQ_REL,
                                             __HIP_MEMORY_SCOPE_AGENT) == 511);
        }
        __syncthreads();
        if (amlast) {
            __threadfence();
            float s = partial[t] + partial[t + 256];
            #pragma unroll
            for (int sh = 32; sh; sh >>= 1) s += __shfl_xor(s, sh);
            if (lane == 0) wred[wv] = s;
            __syncthreads();
            if (t == 0)
                out[0] = (wred[0] + wred[1] + wred[2] + wred[3]) / (float)N_TOT;
        }
    }
}

// ---------------------------------------------------------------------------
extern "C" void kernel_launch(void* const* d_in, const int* in_sizes, int n_in,
                              void* d_out, int out_size, void* d_ws, size_t ws_size,
                              hipStream_t stream)
{
    const float* z_i  = (const float*)d_in[0];
    const float* z_j  = (const float*)d_in[1];
    // d_in[2] (z_n) unused by the reference
    const float* dist = (const float*)d_in[3];

    char* ws = (char*)d_ws;
    unsigned short* zb = (unsigned short*)ws;                                   // 2 MB
    float* zf        = (float*)(ws + 2u * 1024 * 1024);                         // 4 MB
    int*   lab       = (int*)  (ws + 6u * 1024 * 1024);                         // 16 KB
    float* csum_part = (float*)(ws + 6u * 1024 * 1024 + 16 * 1024);             // 400 KB
    float* den_part  = (float*)(ws + 6u * 1024 * 1024 + 416 * 1024);            // 512 KB
    float* partial   = (float*)(ws + 6u * 1024 * 1024 + 928 * 1024);            // 2 KB
    int*   gsync     = (int*)  (ws + 6u * 1024 * 1024 + 932 * 1024);            // 256 B

    float* out = (float*)d_out;

    hipMemsetAsync(gsync, 0, 256, stream);
    hipLaunchKernelGGL(fused_kernel, dim3(NWORK), dim3(256), 0, stream,
                       z_i, z_j, dist, zb, zf, lab,
                       den_part, csum_part, partial, gsync, out);
}

// Round 8
// 122.471 us; speedup vs baseline: 2.8028x; 2.8028x over previous
//
#include <hip/hip_runtime.h>
#include <hip/hip_bf16.h>

#define N_TOT 4096
#define BATCH 2048
#define DIM   256
#define NCLS  100
#define NSLC  4            // csum slices
#define NTILE 32           // 4096 / 128
#define NPAIR 528          // NTILE*(NTILE+1)/2
#define NWORK (NPAIR + NCLS * NSLC)   // 928 blocks
#define NCSUM (NCLS * NSLC)           // 400

typedef __attribute__((ext_vector_type(8))) short short8;
typedef __attribute__((ext_vector_type(4))) float floatx4;
typedef __attribute__((ext_vector_type(4))) unsigned short ushortx4;

typedef __attribute__((address_space(1))) const unsigned int as1c_uint;
typedef __attribute__((address_space(3))) unsigned int as3_uint;

// async global->LDS, 16B per lane; lds dest is wave-uniform base (+lane*16 by HW)
__device__ __forceinline__ void gload_lds16(const void* g, void* lds_base) {
    __builtin_amdgcn_global_load_lds((as1c_uint*)g, (as3_uint*)lds_base, 16, 0, 0);
}

__device__ __forceinline__ unsigned short f2bf(float x) {
    __hip_bfloat16 h = __float2bfloat16(x);
    return *(unsigned short*)&h;
}

__device__ __forceinline__ int agent_add(int* p) {
    return __hip_atomic_fetch_add(p, 1, __ATOMIC_RELAXED, __HIP_MEMORY_SCOPE_AGENT);
}
// relaxed polling (no per-iteration cache maintenance, low rate via s_sleep)
__device__ __forceinline__ void poll_ge(int* p, int v) {
    while (__hip_atomic_load(p, __ATOMIC_RELAXED, __HIP_MEMORY_SCOPE_AGENT) < v)
        __builtin_amdgcn_s_sleep(8);
}

// sync region (ints, zeroed by hipMemsetAsync each call):
//  [p]          panel_cnt[p]      p=0..31  (RMW only)
//  [64+p]       rowblk_cnt[p]              (RMW only)
//  [128]        csum_cnt                   (RMW + <=32 pollers)
//  [160]        cdone                      (RMW only)
//  [256+32p]    panel_flag[p]              (polled; one 128B line each)
#define PANEL_CNT(g,p)  ((g) + (p))
#define ROWBLK_CNT(g,p) ((g) + 64 + (p))
#define CSUM_CNT(g)     ((g) + 128)
#define CDONE(g)        ((g) + 160)
#define PANEL_FLAG(g,p) ((g) + 256 + 32*(p))

// ---------------------------------------------------------------------------
// Single kernel, dependency-chained (no grid barrier):
//   prep (blocks 0..511, 8 rows each) -> panel flags
//   den tiles (0..527) poll 2 flags; csum (528..927) polls 8 flags
//   last den tile per row-panel does phase C; 32nd C does final reduce
// ---------------------------------------------------------------------------
__global__ __launch_bounds__(256, 4) void fused_kernel(
        const float* __restrict__ z_i, const float* __restrict__ z_j,
        const float* __restrict__ dist,
        unsigned short* __restrict__ zb, float* __restrict__ zf,
        int* __restrict__ lab,
        float* __restrict__ den_part, float* __restrict__ csum_part,
        float* __restrict__ partial,          // stride 32 floats (128B/line)
        int* __restrict__ gsync,
        float* __restrict__ out)
{
    __shared__ short tA[2][128 * 32];    // 2 x 8 KB
    __shared__ short tB[2][128 * 32];    // 2 x 8 KB
    __shared__ float red_rs[2][128];
    __shared__ float red_cs[2][128];
    __shared__ float cred[4][DIM];       // csum reduction
    __shared__ float wred[4];
    __shared__ int   shflags[4];

    const int t = threadIdx.x;
    const int lane = t & 63, wv = t >> 6;
    const int blk = blockIdx.x;

    // ===================== prep (blocks 0..511) =====================
    if (blk < 512) {
        #pragma unroll
        for (int it = 0; it < 2; ++it) {
            const int n = blk * 8 + it * 4 + wv;
            const float* src = (n < BATCH) ? (z_i + (size_t)n * DIM)
                                           : (z_j + (size_t)(n - BATCH) * DIM);
            const floatx4 v = *(const floatx4*)(src + lane * 4);
            float sq = v[0]*v[0] + v[1]*v[1] + v[2]*v[2] + v[3]*v[3];
            #pragma unroll
            for (int s = 32; s; s >>= 1) sq += __shfl_xor(sq, s);
            const float rn = 1.0f / sqrtf(sq);

            floatx4 zn;
            zn[0] = v[0]*rn; zn[1] = v[1]*rn; zn[2] = v[2]*rn; zn[3] = v[3]*rn;
            *(floatx4*)(zf + (size_t)n * DIM + lane * 4) = zn;
            ushortx4 zp;
            zp[0] = f2bf(zn[0]); zp[1] = f2bf(zn[1]);
            zp[2] = f2bf(zn[2]); zp[3] = f2bf(zn[3]);
            *(ushortx4*)(zb + (size_t)n * DIM + lane * 4) = zp;

            if (n < BATCH) {
                float d0 = 0.f, d1 = 0.f;
                if (lane < 50) {
                    d0 = dist[(size_t)n * NCLS + 2 * lane];
                    d1 = dist[(size_t)n * NCLS + 2 * lane + 1];
                }
                const unsigned long long m0 = __ballot(d0 > 0.5f);
                const unsigned long long m1 = __ballot(d1 > 0.5f);
                if (lane == 0) {
                    const int l = m0 ? 2 * __builtin_ctzll(m0)
                                     : 2 * __builtin_ctzll(m1) + 1;
                    lab[n] = l;
                    lab[n + BATCH] = l;
                }
            }
        }
        __syncthreads();               // drain all waves' stores to L2
        if (t == 0) {
            __threadfence();           // wbl2: push block's data to coherence pt
            const int p = blk >> 4;
            // panels 0..15 need 16 arrivals; 16..31 need 32 (data + mirror lab)
            if (agent_add(PANEL_CNT(gsync, p)) == (p < 16 ? 15 : 31))
                __hip_atomic_store(PANEL_FLAG(gsync, p), 1,
                                   __ATOMIC_RELAXED, __HIP_MEMORY_SCOPE_AGENT);
            if (p < 16) {
                if (agent_add(PANEL_CNT(gsync, p + 16)) == 31)
                    __hip_atomic_store(PANEL_FLAG(gsync, p + 16), 1,
                                       __ATOMIC_RELAXED, __HIP_MEMORY_SCOPE_AGENT);
            }
        }
    }

    // phase C (runs on the last den tile completing a row-panel)
    auto PHASEC = [&](int p) {
        if (t == 0) poll_ge(CSUM_CNT(gsync), NCSUM);
        __syncthreads();
        float bsum = 0.f;
        const int nbase = p * 128 + wv * 32;
        for (int k = 0; k < 32; ++k) {
            const int n = nbase + k;
            const int c = lab[n];
            const floatx4 zv = *(const floatx4*)(zf + (size_t)n * DIM + lane * 4);
            floatx4 sv = {0.f, 0.f, 0.f, 0.f};
            #pragma unroll
            for (int s = 0; s < NSLC; ++s)
                sv += *(const floatx4*)(csum_part + ((size_t)s * NCLS + c) * DIM + lane * 4);
            float pd = zv[0]*sv[0] + zv[1]*sv[1] + zv[2]*sv[2] + zv[3]*sv[3];
            float dd = (lane < 32) ? den_part[(size_t)lane * N_TOT + n] : 0.f;
            #pragma unroll
            for (int sh = 32; sh; sh >>= 1) {
                pd += __shfl_xor(pd, sh);
                dd += __shfl_xor(dd, sh);
            }
            bsum += (pd - 1.0f) / dd;
        }
        if (lane == 0) wred[wv] = bsum;
        __syncthreads();
        if (t == 0) {
            partial[p * 32] = wred[0] + wred[1] + wred[2] + wred[3];
            __threadfence();
            shflags[2] = (agent_add(CDONE(gsync)) == 31);
        }
        __syncthreads();
        if (shflags[2]) {
            if (t == 0) __threadfence();   // acquire before reading partials
            __syncthreads();
            if (wv == 0) {
                float s = (lane < 32) ? partial[lane * 32] : 0.f;
                #pragma unroll
                for (int sh = 32; sh; sh >>= 1) s += __shfl_xor(s, sh);
                if (lane == 0) out[0] = s / (float)N_TOT;
            }
        }
    };

    if (blk >= NPAIR) {
        // ===================== csum path =====================
        const int b = blk - NPAIR;                 // 0..399
        const int c = b % NCLS;
        const int s = b / NCLS;
        if (t == 0) {
            #pragma unroll
            for (int q = 0; q < 8; ++q)
                poll_ge(PANEL_FLAG(gsync, s * 8 + q), 1);
        }
        __syncthreads();

        const int m0 = s * 1024 + wv * 256;
        floatx4 acc = {0.f, 0.f, 0.f, 0.f};
        #pragma unroll
        for (int g = 0; g < 4; ++g) {
            const int m = m0 + g * 64 + lane;
            unsigned long long mask = __ballot(lab[m] == c);
            while (mask) {
                const int bit = __builtin_ctzll(mask);
                mask &= mask - 1;
                const int mm = m0 + g * 64 + bit;
                acc += *(const floatx4*)(zf + (size_t)mm * DIM + lane * 4);
            }
        }
        *(floatx4*)&cred[wv][lane * 4] = acc;
        __syncthreads();
        if (t < DIM)
            csum_part[((size_t)s * NCLS + c) * DIM + t] =
                cred[0][t] + cred[1][t] + cred[2][t] + cred[3][t];
        __syncthreads();
        if (t == 0) {
            __threadfence();
            agent_add(CSUM_CNT(gsync));
        }
        return;
    }

    // ===================== den path =====================
    int p = blk;
    int bi = 0;
    while (p >= NTILE - bi) { p -= NTILE - bi; ++bi; }
    const int bj = bi + p;

    if (t == 0) {
        poll_ge(PANEL_FLAG(gsync, bi), 1);
        poll_ge(PANEL_FLAG(gsync, bj), 1);
    }
    __syncthreads();

    const int wy = wv >> 1, wx = wv & 1;
    const int lr = lane & 15;
    const int lg = lane >> 4;            // 0..3  (16B chunk of the K=32 slab)
    const int sr = lane >> 2;            // 0..15 row-in-q for staging
    const int sslot = lane & 3;          // LDS slot for staging

    const short* z = (const short*)zb;
    const int row0 = bi * 128;
    const int col0 = bj * 128;

    floatx4 acc[4][4] = {};

    auto STAGE = [&](int kt, int buf) {
        #pragma unroll
        for (int qi = 0; qi < 2; ++qi) {
            const int q = wv * 2 + qi;               // 0..7, 1 KB each (16 rows)
            const int r = q * 16 + sr;
            const int g = sslot ^ ((r >> 1) & 3);    // global chunk for this slot
            gload_lds16(z + (size_t)(row0 + r) * DIM + kt * 32 + g * 8,
                        (char*)tA[buf] + q * 1024);
            gload_lds16(z + (size_t)(col0 + r) * DIM + kt * 32 + g * 8,
                        (char*)tB[buf] + q * 1024);
        }
    };
    auto COMPUTE = [&](int buf) {
        short8 a[4], bb[4];
        #pragma unroll
        for (int i = 0; i < 4; ++i) {
            const int row = wy * 64 + i * 16 + lr;
            const int sl  = lg ^ ((row >> 1) & 3);
            a[i] = *(const short8*)((const char*)tA[buf] + row * 64 + sl * 16);
        }
        #pragma unroll
        for (int j = 0; j < 4; ++j) {
            const int col = wx * 64 + j * 16 + lr;
            const int sl  = lg ^ ((col >> 1) & 3);
            bb[j] = *(const short8*)((const char*)tB[buf] + col * 64 + sl * 16);
        }
        #pragma unroll
        for (int i = 0; i < 4; ++i)
            #pragma unroll
            for (int j = 0; j < 4; ++j)
                acc[i][j] = __builtin_amdgcn_mfma_f32_16x16x32_bf16(a[i], bb[j], acc[i][j], 0, 0, 0);
    };

    STAGE(0, 0);
    __syncthreads();
    int cur = 0;
    #pragma unroll
    for (int kt = 0; kt < 8; ++kt) {
        if (kt < 7) STAGE(kt + 1, cur ^ 1);
        COMPUTE(cur);
        __syncthreads();
        cur ^= 1;
    }

    // epilogue: e = off-diag exp(sim); row sums + col sums
    float rs[4][4] = {};
    float cs[4]    = {};
    #pragma unroll
    for (int i = 0; i < 4; ++i) {
        #pragma unroll
        for (int j = 0; j < 4; ++j) {
            const int gcol = col0 + wx * 64 + j * 16 + lr;
            #pragma unroll
            for (int r = 0; r < 4; ++r) {
                const int grow = row0 + wy * 64 + i * 16 + lg * 4 + r;
                const float e = (grow == gcol) ? 0.0f : __expf(acc[i][j][r]);
                rs[i][r] += e;
                cs[j]    += e;
            }
        }
    }
    #pragma unroll
    for (int i = 0; i < 4; ++i)
        #pragma unroll
        for (int r = 0; r < 4; ++r) {
            float v = rs[i][r];
            v += __shfl_xor(v, 1); v += __shfl_xor(v, 2);
            v += __shfl_xor(v, 4); v += __shfl_xor(v, 8);
            rs[i][r] = v;
        }
    if (lr == 0)
        #pragma unroll
        for (int i = 0; i < 4; ++i)
            #pragma unroll
            for (int r = 0; r < 4; ++r)
                red_rs[wx][wy * 64 + i * 16 + lg * 4 + r] = rs[i][r];

    #pragma unroll
    for (int j = 0; j < 4; ++j) {
        float v = cs[j];
        v += __shfl_xor(v, 16); v += __shfl_xor(v, 32);
        cs[j] = v;
    }
    if (lane < 16)
        #pragma unroll
        for (int j = 0; j < 4; ++j)
            red_cs[wy][wx * 64 + j * 16 + lr] = cs[j];

    __syncthreads();
    if (t < 128) {
        den_part[(size_t)bj * N_TOT + row0 + t] = red_rs[0][t] + red_rs[1][t];
        if (bi != bj)
            den_part[(size_t)bi * N_TOT + col0 + t] = red_cs[0][t] + red_cs[1][t];
    }
    __syncthreads();                   // drain den_part stores
    if (t == 0) {
        __threadfence();               // release den_part
        shflags[0] = (agent_add(ROWBLK_CNT(gsync, bi)) == 31);
        shflags[1] = (bi != bj) ? (agent_add(ROWBLK_CNT(gsync, bj)) == 31) : 0;
    }
    __syncthreads();
    if (shflags[0]) PHASEC(bi);
    if (shflags[1]) PHASEC(bj);
}

// ---------------------------------------------------------------------------
extern "C" void kernel_launch(void* const* d_in, const int* in_sizes, int n_in,
                              void* d_out, int out_size, void* d_ws, size_t ws_size,
                              hipStream_t stream)
{
    const float* z_i  = (const float*)d_in[0];
    const float* z_j  = (const float*)d_in[1];
    // d_in[2] (z_n) unused by the reference
    const float* dist = (const float*)d_in[3];

    char* ws = (char*)d_ws;
    unsigned short* zb = (unsigned short*)ws;                                   // 2 MB
    float* zf        = (float*)(ws + 2u * 1024 * 1024);                         // 4 MB
    int*   lab       = (int*)  (ws + 6u * 1024 * 1024);                         // 16 KB
    float* csum_part = (float*)(ws + 6u * 1024 * 1024 + 16 * 1024);             // 400 KB
    float* den_part  = (float*)(ws + 6u * 1024 * 1024 + 416 * 1024);            // 512 KB
    float* partial   = (float*)(ws + 6u * 1024 * 1024 + 928 * 1024);            // 4 KB (padded)
    int*   gsync     = (int*)  (ws + 6u * 1024 * 1024 + 932 * 1024);            // 8 KB

    float* out = (float*)d_out;

    hipMemsetAsync(gsync, 0, 8192, stream);
    hipLaunchKernelGGL(fused_kernel, dim3(NWORK), dim3(256), 0, stream,
                       z_i, z_j, dist, zb, zf, lab,
                       den_part, csum_part, partial, gsync, out);
}

// Round 9
// 38.661 us; speedup vs baseline: 8.8788x; 3.1678x over previous
//
#include <hip/hip_runtime.h>
#include <hip/hip_bf16.h>

#define N_TOT 4096
#define BATCH 2048
#define DIM   256
#define NCLS  100
#define NSLC  4            // csum slices
#define NTILE 16           // 4096 / 256
#define NPAIR 136          // NTILE*(NTILE+1)/2
#define NWORK (NPAIR + NCLS * NSLC)   // 536 blocks

typedef __attribute__((ext_vector_type(8))) short short8;
typedef __attribute__((ext_vector_type(4))) float floatx4;
typedef __attribute__((ext_vector_type(4))) unsigned short ushortx4;

typedef __attribute__((address_space(1))) const unsigned int as1c_uint;
typedef __attribute__((address_space(3))) unsigned int as3_uint;

// async global->LDS, 16B per lane; lds dest is wave-uniform base (+lane*16 by HW)
__device__ __forceinline__ void gload_lds16(const void* g, void* lds_base) {
    __builtin_amdgcn_global_load_lds((as1c_uint*)g, (as3_uint*)lds_base, 16, 0, 0);
}

__device__ __forceinline__ unsigned short f2bf(float x) {
    __hip_bfloat16 h = __float2bfloat16(x);
    return *(unsigned short*)&h;
}

// ---------------------------------------------------------------------------
// K1: normalize rows of concat(z_i, z_j). Wave-per-row; bf16+fp32 copies;
//     labels via ballot; zero final counter.
// ---------------------------------------------------------------------------
__global__ __launch_bounds__(256) void prep_kernel(const float* __restrict__ z_i,
                                                   const float* __restrict__ z_j,
                                                   const float* __restrict__ dist,
                                                   unsigned short* __restrict__ zb,
                                                   float* __restrict__ zf,
                                                   int* __restrict__ lab,
                                                   int* __restrict__ counter)
{
    const int t = threadIdx.x;
    const int lane = t & 63, wv = t >> 6;
    if (blockIdx.x == 0 && t == 0) *counter = 0;

    #pragma unroll
    for (int it = 0; it < 2; ++it) {
        const int n = blockIdx.x * 8 + it * 4 + wv;
        const float* src = (n < BATCH) ? (z_i + (size_t)n * DIM)
                                       : (z_j + (size_t)(n - BATCH) * DIM);
        const floatx4 v = *(const floatx4*)(src + lane * 4);
        float ss = v[0]*v[0] + v[1]*v[1] + v[2]*v[2] + v[3]*v[3];
        #pragma unroll
        for (int s = 32; s; s >>= 1) ss += __shfl_xor(ss, s);
        const float rn = 1.0f / sqrtf(ss);

        floatx4 zn;
        zn[0] = v[0]*rn; zn[1] = v[1]*rn; zn[2] = v[2]*rn; zn[3] = v[3]*rn;
        *(floatx4*)(zf + (size_t)n * DIM + lane * 4) = zn;
        ushortx4 zp;
        zp[0] = f2bf(zn[0]); zp[1] = f2bf(zn[1]);
        zp[2] = f2bf(zn[2]); zp[3] = f2bf(zn[3]);
        *(ushortx4*)(zb + (size_t)n * DIM + lane * 4) = zp;

        if (n < BATCH) {
            float d0 = 0.f, d1 = 0.f;
            if (lane < 50) {
                d0 = dist[(size_t)n * NCLS + 2 * lane];
                d1 = dist[(size_t)n * NCLS + 2 * lane + 1];
            }
            const unsigned long long m0 = __ballot(d0 > 0.5f);
            const unsigned long long m1 = __ballot(d1 > 0.5f);
            if (lane == 0) {
                const int l = m0 ? 2 * __builtin_ctzll(m0)
                                 : 2 * __builtin_ctzll(m1) + 1;
                lab[n] = l;
                lab[n + BATCH] = l;
            }
        }
    }
}

// ---------------------------------------------------------------------------
// K2 (fused): blocks [0,NPAIR) = den MFMA 256x256 tiles (8 waves);
//             [NPAIR,NWORK) = class sums.
//     den: BK=32 double-buffered LDS; swizzle: 64B rows of 4x16B chunks,
//     slot = chunk ^ ((row>>1)&3), inverse applied on the global source.
// ---------------------------------------------------------------------------
__global__ __launch_bounds__(512, 2) void work_kernel(const __hip_bfloat16* __restrict__ zbp,
                                                      const float* __restrict__ zf,
                                                      const int* __restrict__ lab,
                                                      float* __restrict__ den_part,
                                                      float* __restrict__ csum_part)
{
    __shared__ short tA[2][256 * 32];    // 2 x 16 KB
    __shared__ short tB[2][256 * 32];    // 2 x 16 KB
    __shared__ float red_rs[2][256];     // 2 KB  (col-half partial row sums)
    __shared__ float red_cs[4][256];     // 4 KB  (row-strip partial col sums)
    __shared__ float cred[8][DIM];       // 8 KB  (csum reduction)

    const int t = threadIdx.x;
    const int lane = t & 63, wv = t >> 6;

    if (blockIdx.x >= NPAIR) {
        // ---------------- csum path ----------------
        const int b = blockIdx.x - NPAIR;          // 0..399
        const int c = b % NCLS;
        const int s = b / NCLS;
        const int m0 = s * 1024 + wv * 128;

        floatx4 acc = {0.f, 0.f, 0.f, 0.f};
        #pragma unroll
        for (int g = 0; g < 2; ++g) {
            const int m = m0 + g * 64 + lane;
            unsigned long long mask = __ballot(lab[m] == c);
            while (mask) {
                const int bit = __builtin_ctzll(mask);
                mask &= mask - 1;
                const int mm = m0 + g * 64 + bit;
                acc += *(const floatx4*)(zf + (size_t)mm * DIM + lane * 4);
            }
        }
        *(floatx4*)&cred[wv][lane * 4] = acc;
        __syncthreads();
        if (t < DIM) {
            float v = 0.f;
            #pragma unroll
            for (int w = 0; w < 8; ++w) v += cred[w][t];
            csum_part[((size_t)s * NCLS + c) * DIM + t] = v;
        }
        return;
    }

    // ---------------- den path ----------------
    int p = blockIdx.x;
    int bi = 0;
    while (p >= NTILE - bi) { p -= NTILE - bi; ++bi; }
    const int bj = bi + p;

    const int wy = wv & 3;               // row strip (4 x 64 rows)
    const int wx = wv >> 2;              // col half  (2 x 128 cols)
    const int lr = lane & 15;
    const int lg = lane >> 4;            // 0..3  (16B chunk of the K=32 slab)
    const int sr = lane >> 2;            // 0..15 row-in-q for staging
    const int sslot = lane & 3;          // LDS slot for staging

    const short* z = (const short*)zbp;
    const int row0 = bi * 256;
    const int col0 = bj * 256;

    floatx4 acc[4][8] = {};

    auto STAGE = [&](int kt, int buf) {
        #pragma unroll
        for (int qi = 0; qi < 2; ++qi) {
            const int q = wv * 2 + qi;               // 0..15, 1 KB each (16 rows)
            const int r = q * 16 + sr;
            const int g = sslot ^ ((r >> 1) & 3);    // global chunk for this slot
            gload_lds16(z + (size_t)(row0 + r) * DIM + kt * 32 + g * 8,
                        (char*)tA[buf] + q * 1024);
            gload_lds16(z + (size_t)(col0 + r) * DIM + kt * 32 + g * 8,
                        (char*)tB[buf] + q * 1024);
        }
    };
    auto COMPUTE = [&](int buf) {
        short8 a[4], bb[8];
        #pragma unroll
        for (int i = 0; i < 4; ++i) {
            const int row = wy * 64 + i * 16 + lr;
            const int sl  = lg ^ ((row >> 1) & 3);
            a[i] = *(const short8*)((const char*)tA[buf] + row * 64 + sl * 16);
        }
        #pragma unroll
        for (int j = 0; j < 8; ++j) {
            const int col = wx * 128 + j * 16 + lr;
            const int sl  = lg ^ ((col >> 1) & 3);
            bb[j] = *(const short8*)((const char*)tB[buf] + col * 64 + sl * 16);
        }
        #pragma unroll
        for (int i = 0; i < 4; ++i)
            #pragma unroll
            for (int j = 0; j < 8; ++j)
                acc[i][j] = __builtin_amdgcn_mfma_f32_16x16x32_bf16(a[i], bb[j], acc[i][j], 0, 0, 0);
    };

    STAGE(0, 0);
    __syncthreads();
    int cur = 0;
    #pragma unroll
    for (int kt = 0; kt < 8; ++kt) {
        if (kt < 7) STAGE(kt + 1, cur ^ 1);
        COMPUTE(cur);
        __syncthreads();
        cur ^= 1;
    }

    // ---- epilogue: e = off-diag exp(sim); row sums + col sums
    float rs[4][4] = {};       // [i][r]
    float cs[8]    = {};       // [j]
    #pragma unroll
    for (int i = 0; i < 4; ++i) {
        #pragma unroll
        for (int j = 0; j < 8; ++j) {
            const int gcol = col0 + wx * 128 + j * 16 + lr;
            #pragma unroll
            for (int r = 0; r < 4; ++r) {
                const int grow = row0 + wy * 64 + i * 16 + lg * 4 + r;
                const float e = (grow == gcol) ? 0.0f : __expf(acc[i][j][r]);
                rs[i][r] += e;
                cs[j]    += e;
            }
        }
    }
    // row sums: reduce across the 16 col-lanes (lr bits) of each lg group
    #pragma unroll
    for (int i = 0; i < 4; ++i)
        #pragma unroll
        for (int r = 0; r < 4; ++r) {
            float v = rs[i][r];
            v += __shfl_xor(v, 1); v += __shfl_xor(v, 2);
            v += __shfl_xor(v, 4); v += __shfl_xor(v, 8);
            rs[i][r] = v;
        }
    if (lr == 0)
        #pragma unroll
        for (int i = 0; i < 4; ++i)
            #pragma unroll
            for (int r = 0; r < 4; ++r)
                red_rs[wx][wy * 64 + i * 16 + lg * 4 + r] = rs[i][r];

    // col sums: reduce across the 4 lg row-groups (lane bits 4,5)
    #pragma unroll
    for (int j = 0; j < 8; ++j) {
        float v = cs[j];
        v += __shfl_xor(v, 16); v += __shfl_xor(v, 32);
        cs[j] = v;
    }
    if (lane < 16)
        #pragma unroll
        for (int j = 0; j < 8; ++j)
            red_cs[wy][wx * 128 + j * 16 + lr] = cs[j];

    __syncthreads();
    if (t < 256) {
        den_part[(size_t)bj * N_TOT + row0 + t] = red_rs[0][t] + red_rs[1][t];
        if (bi != bj)
            den_part[(size_t)bi * N_TOT + col0 + t] =
                red_cs[0][t] + red_cs[1][t] + red_cs[2][t] + red_cs[3][t];
    }
}

// ---------------------------------------------------------------------------
// K3: per-row finalize + last-block final reduce (deterministic values).
//     nom = zf[n].csum[lab[n]] - 1; den = sum of NTILE row-panel partials.
// ---------------------------------------------------------------------------
__global__ __launch_bounds__(256) void final_kernel(const float* __restrict__ zf,
                                                    const int* __restrict__ lab,
                                                    const float* __restrict__ csum_part,
                                                    const float* __restrict__ den_part,
                                                    float* __restrict__ partial,
                                                    int* __restrict__ counter,
                                                    float* __restrict__ out)
{
    const int t = threadIdx.x;
    const int lane = t & 63, wv = t >> 6;

    float bsum = 0.0f;
    #pragma unroll
    for (int it = 0; it < 2; ++it) {
        const int n = blockIdx.x * 8 + it * 4 + wv;
        const int c = lab[n];

        const floatx4 zv = *(const floatx4*)(zf + (size_t)n * DIM + lane * 4);
        floatx4 sv = {0.f, 0.f, 0.f, 0.f};
        #pragma unroll
        for (int s = 0; s < NSLC; ++s)
            sv += *(const floatx4*)(csum_part + ((size_t)s * NCLS + c) * DIM + lane * 4);

        float pd = zv[0]*sv[0] + zv[1]*sv[1] + zv[2]*sv[2] + zv[3]*sv[3];
        float dd = (lane < NTILE) ? den_part[(size_t)lane * N_TOT + n] : 0.0f;
        #pragma unroll
        for (int sh = 32; sh; sh >>= 1) {
            pd += __shfl_xor(pd, sh);
            dd += __shfl_xor(dd, sh);
        }
        bsum += (pd - 1.0f) / dd;
    }

    __shared__ float w[4];
    __shared__ int amlast;
    if (lane == 0) w[wv] = bsum;
    __syncthreads();
    if (t == 0) {
        partial[blockIdx.x] = w[0] + w[1] + w[2] + w[3];
        __threadfence();
        amlast = (atomicAdd(counter, 1) == (int)gridDim.x - 1);
    }
    __syncthreads();
    if (amlast) {
        __threadfence();
        float s = partial[t] + partial[t + 256];
        #pragma unroll
        for (int sh = 32; sh; sh >>= 1) s += __shfl_xor(s, sh);
        if (lane == 0) w[wv] = s;
        __syncthreads();
        if (t == 0)
            out[0] = (w[0] + w[1] + w[2] + w[3]) / (float)N_TOT;
    }
}

// ---------------------------------------------------------------------------
extern "C" void kernel_launch(void* const* d_in, const int* in_sizes, int n_in,
                              void* d_out, int out_size, void* d_ws, size_t ws_size,
                              hipStream_t stream)
{
    const float* z_i  = (const float*)d_in[0];
    const float* z_j  = (const float*)d_in[1];
    // d_in[2] (z_n) unused by the reference
    const float* dist = (const float*)d_in[3];

    char* ws = (char*)d_ws;
    unsigned short* zb = (unsigned short*)ws;                                   // 2 MB
    float* zf        = (float*)(ws + 2u * 1024 * 1024);                         // 4 MB
    int*   lab       = (int*)  (ws + 6u * 1024 * 1024);                         // 16 KB
    float* csum_part = (float*)(ws + 6u * 1024 * 1024 + 16 * 1024);             // 400 KB
    float* den_part  = (float*)(ws + 6u * 1024 * 1024 + 416 * 1024);            // 256 KB (16 panels)
    float* partial   = (float*)(ws + 6u * 1024 * 1024 + 928 * 1024);            // 2 KB
    int*   counter   = (int*)  (ws + 6u * 1024 * 1024 + 930 * 1024);            // 4 B

    float* out = (float*)d_out;

    hipLaunchKernelGGL(prep_kernel, dim3(512), dim3(256), 0, stream,
                       z_i, z_j, dist, zb, zf, lab, counter);
    hipLaunchKernelGGL(work_kernel, dim3(NWORK), dim3(512), 0, stream,
                       (const __hip_bfloat16*)zb, zf, lab, den_part, csum_part);
    hipLaunchKernelGGL(final_kernel, dim3(N_TOT / 8), dim3(256), 0, stream,
                       zf, lab, csum_part, den_part, partial, counter, out);
}